// Round 8
// baseline (164.977 us; speedup 1.0000x reference)
//
#include <hip/hip_runtime.h>
#include <stdint.h>

// FC tensor product as on-the-fly-A GEMMs, f16, MFMA f32_16x16x32_f16.
// R8: 4 blocks/CU (16 waves) for bubble decorrelation. Block = 128 rows x
// 64 cols, 4 waves = 2 row-halves x 2 n-halves, cooperative W staging
// (duplication stays in-CU/L1), 40KB LDS (4x8KB pair slots + 8KB a slots),
// counted vmcnt FIFO depth-3, barrier per macro, XCD-swizzled 1024-block grid.

typedef _Float16 f16;
typedef f16 f16x8 __attribute__((ext_vector_type(8)));
typedef float f32x4 __attribute__((ext_vector_type(4)));
typedef int i32x4 __attribute__((ext_vector_type(4)));

#define OFF_W000 0u               // [h2][vh2][u128][p2][q4][n64][8]
#define OFF_W110 2097152u         // [h2][u64][p2][q4][n64][8]
#define OFF_W011 2621440u         // [u128][p][q][n64][8]
#define OFF_W101 3145728u         // [u=s2 128][p][q][n64][8]
#define OFF_W111 3670016u         // [u64][p][q][n64][8]
#define OFF_XS1  3932160u         // [rt64][uo16][r128][8]
#define OFF_XS2  4980736u
#define OFF_XV1  6029312u         // [rt][i3][ov8][r128][8]
#define OFF_XV2  7602176u
#define OFF_S0A  9175040u
#define OFF_S0B  10223616u
#define OFF_S1O  13369344u
#define WS_ELEMS 14942208u

#define SC_0E 0.006987712429686843f
#define SC_1O 0.0078125f
#define SC_1E 0.011048543456039806f

// ---------------- pre-kernel: retile everything to f16 ----------------
// total threads = 9175040 = 35840 blocks * 256 (every branch bound exact)
__global__ void tile_all_k(const float* __restrict__ w000, const float* __restrict__ w011,
                           const float* __restrict__ w101, const float* __restrict__ w110,
                           const float* __restrict__ w111, const float* __restrict__ x1,
                           const float* __restrict__ x2, f16* __restrict__ ws)
{
  unsigned tid = blockIdx.x*256u + threadIdx.x;
  if (tid < 2097152u) {  // W000t [h][vh][u][p][q][n64][8]
    unsigned e=tid&7u, n=(tid>>3)&63u, q=(tid>>9)&3u, p=(tid>>11)&1u,
             u=(tid>>12)&127u, vh=(tid>>19)&1u, h=(tid>>20)&1u;
    unsigned v = vh*64u + p*32u + q*8u + e;
    ws[OFF_W000+tid] = (f16)w000[u*16384u + v*128u + h*64u + n];
    return;
  }
  tid -= 2097152u;
  if (tid < 524288u) {   // W110t [h][u64][p][q][n64][8], fold 1/sqrt3
    unsigned e=tid&7u, n=(tid>>3)&63u, q=(tid>>9)&3u, p=(tid>>11)&1u,
             u=(tid>>12)&63u, h=(tid>>18)&1u;
    unsigned v = p*32u + q*8u + e;
    ws[OFF_W110+tid] = (f16)(w110[u*8192u + v*128u + h*64u + n] * 0.5773502691896258f);
    return;
  }
  tid -= 524288u;
  if (tid < 524288u) {   // W011t [u128][p][q][n64][8]
    unsigned e=tid&7u, n=(tid>>3)&63u, q=(tid>>9)&3u, p=(tid>>11)&1u, u=tid>>12;
    unsigned v = p*32u + q*8u + e;
    ws[OFF_W011+tid] = (f16)w011[u*4096u + v*64u + n];
    return;
  }
  tid -= 524288u;
  if (tid < 524288u) {   // W101t [u=s2 128][p][q][n64][8]  (transposed)
    unsigned e=tid&7u, n=(tid>>3)&63u, q=(tid>>9)&3u, p=(tid>>11)&1u, u=tid>>12;
    unsigned v = p*32u + q*8u + e;   // v1 index
    ws[OFF_W101+tid] = (f16)w101[v*8192u + u*64u + n];
    return;
  }
  tid -= 524288u;
  if (tid < 262144u) {   // W111t [u64][p][q][n64][8]
    unsigned e=tid&7u, n=(tid>>3)&63u, q=(tid>>9)&3u, p=(tid>>11)&1u, u=tid>>12;
    unsigned v = p*32u + q*8u + e;
    ws[OFF_W111+tid] = (f16)w111[u*4096u + v*64u + n];
    return;
  }
  tid -= 262144u;
  if (tid < 1048576u) {  // xs1 [rt][uo16][r128][8]
    unsigned e=tid&7u, r=(tid>>3)&127u, uo=(tid>>10)&15u, rt=tid>>14;
    ws[OFF_XS1+tid] = (f16)x1[(rt*128u+r)*320u + uo*8u + e];
    return;
  }
  tid -= 1048576u;
  if (tid < 1572864u) {  // xv1 [rt][i3][ov8][r128][8]
    unsigned e=tid&7u, r=(tid>>3)&127u, ov=(tid>>10)&7u, rest=tid>>13;
    unsigned i=rest%3u, rt=rest/3u;
    ws[OFF_XV1+tid] = (f16)x1[(rt*128u+r)*320u + 128u + (ov*8u+e)*3u + i];
    return;
  }
  tid -= 1572864u;
  if (tid < 1048576u) {  // xs2
    unsigned e=tid&7u, r=(tid>>3)&127u, uo=(tid>>10)&15u, rt=tid>>14;
    ws[OFF_XS2+tid] = (f16)x2[(rt*128u+r)*320u + uo*8u + e];
    return;
  }
  tid -= 1048576u;
  {                      // xv2
    unsigned e=tid&7u, r=(tid>>3)&127u, ov=(tid>>10)&7u, rest=tid>>13;
    unsigned i=rest%3u, rt=rest/3u;
    ws[OFF_XV2+tid] = (f16)x2[(rt*128u+r)*320u + 128u + (ov*8u+e)*3u + i];
  }
}

// ---------------- main kernel ----------------
#define GLD16(g,l) __builtin_amdgcn_global_load_lds( \
    (const __attribute__((address_space(1))) unsigned int*)(g), \
    (__attribute__((address_space(3))) unsigned int*)(l), 16, 0, 0)

#define WAITV(n) asm volatile("s_waitcnt vmcnt(" #n ")" ::: "memory")

// One phase: acc += A*W.  SS supersteps x 8 macros; macro = one u, K=64.
// 4 waves cooperative: wave stages 2KB chunk of each 8KB pair (2 GLD16).
// FIFO (per wave, depth-3 prefetch; issues per pair = 2, stA = 1):
//   prologue: stA(0),P(0),P(1),P(2)  -> entering macro 0: WAITV(4) drains stA+P0
//   steady top of t: outstanding [P(t),P(t+1),P(t+2)] -> WAITV(4) drains P(t)
//   kc==7: [P(t),P(t+1),stA,P(t+2)] -> WAITV(5); kc==0: WAITV(4) drains P+stA
//   tail (last ss): kc==6 -> WAITV(2), kc==7 -> WAITV(0)
//   body: [kc==6: stA(ss+1)] then P(t+3) -> slot (kc+3)&3
template<bool NEG, int SS>
__device__ __forceinline__ void run_phase(const f16* __restrict__ Wt,
    const f16* __restrict__ aW, const f16* __restrict__ bW, int bRow, int nh,
    f16* sW, f16* sAw, f32x4 (&acc)[4][2], int lane, int wid)
{
  constexpr int M = SS*8;
  const int q = lane >> 4, r15 = lane & 15;

  WAITV(0);   // drain prior-phase stores/loads for exact counting

  // b octets for the whole phase -> registers (u-independent)
  f16x8 br[4][2];
#pragma unroll
  for (int mt=0; mt<4; ++mt)
#pragma unroll
    for (int o=0; o<2; ++o)
      br[mt][o] = *(const f16x8*)(bW + (o*4+q)*1024 + (bRow + mt*16 + r15)*8);
#pragma unroll
  for (int mt=0; mt<4; ++mt)
#pragma unroll
    for (int o=0; o<2; ++o) {      // force loads complete now (vmcnt -> 0)
      i32x4 tmp = __builtin_bit_cast(i32x4, br[mt][o]);
      asm volatile("" :: "v"(tmp));
    }

  auto stPair = [&](int p, int slot){   // this wave's 2KB chunk of the 8KB pair
    const char* s = (const char*)Wt + p*8192 + wid*2048 + lane*16;
    char* d = (char*)sW + slot*8192 + wid*2048;
    GLD16(s, d);
    GLD16(s + 1024, d + 1024);
  };
  auto stA = [&](int ss2){              // 1KB: this wave's 64 rows x 8 u
    GLD16((const char*)(aW + ss2*1024) + lane*16, (char*)sAw + (ss2&1)*1024);
  };

  stA(0); stPair(0,0); stPair(1,1); stPair(2,2);

  f16x8 aR[4];
#pragma unroll 1
  for (int ss = 0; ss < SS; ++ss) {
#pragma unroll
    for (int kc = 0; kc < 8; ++kc) {
      const int t = ss*8 + kc;
      if (kc == 7)      { if (ss+1 < SS) { WAITV(5); } else { WAITV(0); } }
      else if (kc == 6) { if (ss+1 < SS) { WAITV(4); } else { WAITV(2); } }
      else              { WAITV(4); }
      __builtin_amdgcn_s_barrier();
      __builtin_amdgcn_sched_barrier(0);
      // ---- issues (FIFO order: stA before stPair)
      if (kc == 6 && ss+1 < SS) stA(ss+1);
      if (t + 3 < M) stPair(t+3, (kc+3)&3);
      // ---- a octets for this superstep (stA drained by this macro's WAITV)
      if (kc == 0) {
#pragma unroll
        for (int mt=0; mt<4; ++mt)
          aR[mt] = *(const f16x8*)(sAw + (ss&1)*512 + (mt*16+r15)*8);
      }
      // ---- compute: 4 ds_read_b128 + 16 MFMA
      __builtin_amdgcn_s_setprio(1);
#pragma unroll
      for (int p=0; p<2; ++p) {
        f16x8 af[4];
#pragma unroll
        for (int mt=0; mt<4; ++mt) {
          f16 av = aR[mt][kc];
          if constexpr (NEG) av = -av;
          af[mt] = av * br[mt][p];
        }
#pragma unroll
        for (int nt=0; nt<2; ++nt) {
          f16x8 bw = *(const f16x8*)(sW + (kc&3)*4096 + p*2048 + q*512
                                     + (nh*32 + nt*16 + r15)*8);
#pragma unroll
          for (int mt=0; mt<4; ++mt)
            acc[mt][nt] = __builtin_amdgcn_mfma_f32_16x16x32_f16(af[mt], bw, acc[mt][nt], 0,0,0);
        }
      }
      __builtin_amdgcn_s_setprio(0);
    }
  }
  __builtin_amdgcn_s_barrier();     // protect LDS before next phase / stores
  __builtin_amdgcn_sched_barrier(0);
}

__global__ __launch_bounds__(256, 4)
void tp_main(f16* __restrict__ ws, float* __restrict__ out)
{
  __shared__ f16 smem[20480];       // 40KB: 4 pair slots x 8KB | 4 waves x 2x1KB a
  f16* sW = smem;
  const int lane = threadIdx.x & 63, wid = threadIdx.x >> 6;
  f16* sAw = smem + 16384 + wid*1024;
  const int q = lane >> 4, r15 = lane & 15;
  const int rh = wid & 1, nh = wid >> 1;    // wave -> row-half x n-half

  f32x4 acc[4][2];
#pragma unroll
  for (int a=0;a<4;++a)
#pragma unroll
    for (int b=0;b<2;++b) acc[a][b] = (f32x4){0.f,0.f,0.f,0.f};

  // XCD swizzle (bijective: 1024 = 8*128): same-W-stream blocks share an XCD L2
  const int jid = (blockIdx.x & 7)*128 + (blockIdx.x >> 3);

#define STORE_DIRECT(col_expr, SC)                                        \
  _Pragma("unroll")                                                       \
  for (int mt=0;mt<4;++mt)                                                \
    _Pragma("unroll")                                                     \
    for (int nt=0;nt<2;++nt)                                              \
      _Pragma("unroll")                                                   \
      for (int rg=0;rg<4;++rg)                                            \
        out[(rowb+mt*16+q*4+rg)*512 + (col_expr)] = (SC)*acc[mt][nt][rg];

#define STORE_SLAB(slab, stride, col_expr, SC)                            \
  _Pragma("unroll")                                                       \
  for (int mt=0;mt<4;++mt)                                                \
    _Pragma("unroll")                                                     \
    for (int nt=0;nt<2;++nt)                                              \
      _Pragma("unroll")                                                   \
      for (int rg=0;rg<4;++rg)                                            \
        (slab)[(rowb+mt*16+q*4+rg)*(stride) + (col_expr)] = (f16)((SC)*acc[mt][nt][rg]);

  if (jid < 256) {          // ---- J0a: w000; (h,vh) quarter x rt
    const int quarter = jid >> 6, rt = jid & 63;
    const int h = quarter & 1, vh = quarter >> 1;
    const f16* aW = ws + OFF_XS1 + rt*16384 + rh*512;
    const f16* bW = ws + OFF_XS2 + rt*16384 + vh*8192;
    const f16* Wt = ws + OFF_W000 + h*1048576u + vh*524288u;
    run_phase<false,16>(Wt, aW, bW, rh*64, nh, sW, sAw, acc, lane, wid);
    const int rowb = rt*128 + rh*64;
    if (vh == 0) { STORE_DIRECT(h*64 + nh*32 + nt*16 + r15, SC_0E) }
    else { f16* slab = ws + OFF_S0A; STORE_SLAB(slab, 128, h*64 + nh*32 + nt*16 + r15, SC_0E) }
  } else if (jid < 448) {   // ---- J1o-a: w011 (a=s1, b=v2_i) -> direct out1o
    const int s = jid-256, i = s>>6, rt = s&63;
    const f16* aW = ws + OFF_XS1 + rt*16384 + rh*512;
    const f16* bW = ws + OFF_XV2 + (rt*3+i)*8192;
    run_phase<false,16>(ws + OFF_W011, aW, bW, rh*64, nh, sW, sAw, acc, lane, wid);
    const int rowb = rt*128 + rh*64;
    STORE_DIRECT(128 + 3*(nh*32 + nt*16 + r15) + i, SC_1O)
  } else if (jid < 640) {   // ---- J1o-b: w101 (a=s2, b=v1_i) -> slab S1O
    const int s = jid-448, i = s>>6, rt = s&63;
    const f16* aW = ws + OFF_XS2 + rt*16384 + rh*512;
    const f16* bW = ws + OFF_XV1 + (rt*3+i)*8192;
    run_phase<false,16>(ws + OFF_W101, aW, bW, rh*64, nh, sW, sAw, acc, lane, wid);
    const int rowb = rt*128 + rh*64;
    f16* slab = ws + OFF_S1O;
    STORE_SLAB(slab, 192, 3*(nh*32 + nt*16 + r15) + i, SC_1O)
  } else if (jid < 832) {   // ---- J1e: w111 cross component kk, 2 signed terms
    const int s = jid-640, kk = s>>6, rt = s&63;
    int i = kk+1; if (i>2) i-=3;
    int j = kk+2; if (j>2) j-=3;
    run_phase<false,8>(ws + OFF_W111,
        ws + OFF_XV1 + (rt*3+i)*8192 + rh*512, ws + OFF_XV2 + (rt*3+j)*8192,
        rh*64, nh, sW, sAw, acc, lane, wid);
    run_phase<true,8>(ws + OFF_W111,
        ws + OFF_XV1 + (rt*3+j)*8192 + rh*512, ws + OFF_XV2 + (rt*3+i)*8192,
        rh*64, nh, sW, sAw, acc, lane, wid);
    const int rowb = rt*128 + rh*64;
    STORE_DIRECT(320 + 3*(nh*32 + nt*16 + r15) + kk, SC_1E)
  } else {                  // ---- J0b: w110' comp i; h=0 then h=1 -> slab i
    const int s = jid-832, i = s>>6, rt = s&63;
    const f16* aW = ws + OFF_XV1 + (rt*3+i)*8192 + rh*512;
    const f16* bW = ws + OFF_XV2 + (rt*3+i)*8192;
    const int rowb = rt*128 + rh*64;
    f16* slab = ws + OFF_S0B + (unsigned)i*1048576u;
#pragma unroll 1
    for (int h = 0; h < 2; ++h) {
      run_phase<false,8>(ws + OFF_W110 + (unsigned)h*262144u, aW, bW, rh*64, nh,
                         sW, sAw, acc, lane, wid);
      STORE_SLAB(slab, 128, h*64 + nh*32 + nt*16 + r15, SC_0E)
#pragma unroll
      for (int a=0;a<4;++a)
#pragma unroll
        for (int b=0;b<2;++b) acc[a][b] = (f32x4){0.f,0.f,0.f,0.f};
    }
  }
#undef STORE_DIRECT
#undef STORE_SLAB
}

// ---------------- epilogue: fold f16 partial slabs into out ----------------
__global__ void ep_add(const f16* __restrict__ ws, float* __restrict__ out)
{
  unsigned tid = blockIdx.x*256u + threadIdx.x;
  if (tid < 1048576u) {
    unsigned r = tid>>7, c = tid&127u;
    float s = (float)ws[OFF_S0A+tid] + (float)ws[OFF_S0B+tid]
            + (float)ws[OFF_S0B+1048576u+tid] + (float)ws[OFF_S0B+2097152u+tid];
    out[r*512u+c] += s;
  } else {
    unsigned t2 = tid - 1048576u;
    unsigned r = t2/192u, c = t2 - r*192u;
    out[r*512u+128u+c] += (float)ws[OFF_S1O+t2];
  }
}

extern "C" void kernel_launch(void* const* d_in, const int* in_sizes, int n_in,
                              void* d_out, int out_size, void* d_ws, size_t ws_size,
                              hipStream_t stream)
{
  const float* x1   = (const float*)d_in[0];
  const float* x2   = (const float*)d_in[1];
  const float* w000 = (const float*)d_in[2];
  const float* w011 = (const float*)d_in[3];
  const float* w101 = (const float*)d_in[4];
  const float* w110 = (const float*)d_in[5];
  const float* w111 = (const float*)d_in[6];
  float* out = (float*)d_out;
  f16* ws   = (f16*)d_ws;

  if (ws_size < (size_t)WS_ELEMS * 2) return;   // ~29.9 MB scratch

  tile_all_k<<<35840, 256, 0, stream>>>(w000, w011, w101, w110, w111, x1, x2, ws);
  tp_main<<<1024, 256, 0, stream>>>(ws, out);
  ep_add<<<10240, 256, 0, stream>>>(ws, out);
}